// Round 5
// baseline (71.393 us; speedup 1.0000x reference)
//
#include <hip/hip_runtime.h>
#include <hip/hip_bf16.h>
#include <stdint.h>

#define BB 32
#define NN 1024
#define MM 1024
#define DD 256

typedef __attribute__((ext_vector_type(8))) short short8;
typedef __attribute__((ext_vector_type(4))) float floatx4;

__device__ inline unsigned short f2bf(float x) {
    union { __hip_bfloat16 h; unsigned short u; } cv;
    cv.h = __float2bfloat16(x);
    return cv.u;
}

// ---------------------------------------------------------------------------
__global__ __launch_bounds__(256) void init_minbuf(unsigned int* __restrict__ p) {
    p[blockIdx.x * 256 + threadIdx.x] = 0x7F800000u; // +inf
}

// ---------------------------------------------------------------------------
// Convert fp32 -> bf16 + per-row sum of squares (fp32 exact). One wave/row.
// ---------------------------------------------------------------------------
__global__ __launch_bounds__(256) void convert_kernel(
        const float* __restrict__ h1, const float* __restrict__ h2,
        __hip_bfloat16* __restrict__ h1b, __hip_bfloat16* __restrict__ h2b,
        float* __restrict__ sq1, float* __restrict__ sq2) {
    int wave = blockIdx.x * 4 + (threadIdx.x >> 6);
    int lane = threadIdx.x & 63;
    const int total1 = BB * NN;

    const float* src;
    __hip_bfloat16* dst;
    float* sq;
    int row;
    if (wave < total1) { src = h1; dst = h1b; sq = sq1; row = wave; }
    else               { src = h2; dst = h2b; sq = sq2; row = wave - total1; }

    const float4* p = (const float4*)(src + (size_t)row * DD);
    float4 v = p[lane];

    float s = v.x * v.x + v.y * v.y + v.z * v.z + v.w * v.w;
    #pragma unroll
    for (int off = 32; off; off >>= 1) s += __shfl_xor(s, off, 64);

    ushort4 o;
    o.x = f2bf(v.x); o.y = f2bf(v.y); o.z = f2bf(v.z); o.w = f2bf(v.w);
    *(ushort4*)((unsigned short*)(dst + (size_t)row * DD) + lane * 4) = o;

    if (lane == 0) sq[row] = s;
}

// ---------------------------------------------------------------------------
// Barrier-free, LDS-free batched GEMM + fused Hausdorff epilogue.
// Grid (32 batches, 8 n-tiles), 512 threads = 8 waves, 1 block/CU.
// Each wave: 64n x 32m tile, A panel in registers (af[4][8]),
// B fragments loaded global->reg per k-step, ks-level double buffer.
// No __syncthreads, no LDS, no hand-counted vmcnt: waves run free,
// compiler manages waitcnt and software-pipelines.
// ---------------------------------------------------------------------------
__global__ __launch_bounds__(512, 2) void gemm_kernel(
        const __hip_bfloat16* __restrict__ h1b, const __hip_bfloat16* __restrict__ h2b,
        const float* __restrict__ sq1, const float* __restrict__ sq2,
        unsigned int* __restrict__ rowmin, unsigned int* __restrict__ colmin) {
    const int b    = blockIdx.x;       // batch
    const int tile = blockIdx.y;       // n-tile 0..7
    const int n0   = tile * 128;

    const int tid  = threadIdx.x;
    const int wave = tid >> 6;         // 0..7
    const int lane = tid & 63;
    const int wn   = (wave >> 2) * 64;       // {0,64}
    const int wm   = (wave & 3) * 32;        // {0,32,64,96}

    const int krow = lane >> 4;   // 0..3
    const int rrow = lane & 15;   // 0..15
    const int lrow = krow * 4;
    const int lcol = rrow;

    // per-lane base pointers (rows stride 512 B, k-chunk krow*16)
    const char* Abase = (const char*)(h1b + ((size_t)b * NN + n0) * DD)
                      + (size_t)(wn + rrow) * 512 + krow * 16;
    const char* Bbase = (const char*)(h2b + (size_t)b * MM * DD)
                      + (size_t)(wm + rrow) * 512 + krow * 16;

    // s1 norms: rows wn + i*16 + lrow + {0..3}
    const float4* s1p = (const float4*)(sq1 + b * NN + n0 + wn + lrow);
    float4 s1v4[4];
    #pragma unroll
    for (int i = 0; i < 4; ++i) s1v4[i] = s1p[i * 4];

    const float* s2p = sq2 + b * MM + wm + rrow;

    // A panel -> registers: af[i][ksl], ksl = K-slice of 32 (8 slices)
    short8 af[4][8];
    #pragma unroll
    for (int i = 0; i < 4; ++i)
        #pragma unroll
        for (int ksl = 0; ksl < 8; ++ksl)
            af[i][ksl] = *(const short8*)(Abase + (size_t)i * 8192 + ksl * 64);

    // B fragment loader: dst[kk*2+j] for k-step ks of m-tile mt
    #define LOADB(mt_, ks_, BUF)                                              \
        {                                                                     \
            _Pragma("unroll")                                                 \
            for (int kk = 0; kk < 2; ++kk)                                    \
                _Pragma("unroll")                                             \
                for (int j = 0; j < 2; ++j)                                   \
                    BUF[kk * 2 + j] = *(const short8*)(Bbase                  \
                        + (size_t)(mt_) * 65536 + j * 8192                    \
                        + (ks_) * 128 + kk * 64);                             \
        }

    #define COMPUTE(ks_, BUF)                                                 \
        {                                                                     \
            _Pragma("unroll")                                                 \
            for (int kk = 0; kk < 2; ++kk)                                    \
                _Pragma("unroll")                                             \
                for (int i = 0; i < 4; ++i)                                   \
                    _Pragma("unroll")                                         \
                    for (int j = 0; j < 2; ++j)                               \
                        acc[i][j] = __builtin_amdgcn_mfma_f32_16x16x32_bf16(  \
                            af[i][(ks_) * 2 + kk], BUF[kk * 2 + j],           \
                            acc[i][j], 0, 0, 0);                              \
        }

    float rmin[4][4];
    #pragma unroll
    for (int i = 0; i < 4; ++i)
        #pragma unroll
        for (int r = 0; r < 4; ++r) rmin[i][r] = 3.0e38f;

    unsigned int* cm = colmin + b * MM;

    short8 bA[4], bB[4];
    LOADB(0, 0, bA);

    #pragma unroll 1
    for (int mt = 0; mt < 8; ++mt) {
        // sq2 for this m-tile (issued early; used in epilogue far below)
        float s2v0 = s2p[mt * 128];
        float s2v1 = s2p[mt * 128 + 16];

        floatx4 acc[4][2] = {};

        LOADB(mt, 1, bB);
        COMPUTE(0, bA);
        LOADB(mt, 2, bA);
        COMPUTE(1, bB);
        LOADB(mt, 3, bB);
        COMPUTE(2, bA);
        if (mt < 7) LOADB(mt + 1, 0, bA);
        COMPUTE(3, bB);

        // ---- per-mt epilogue: dist + mins ----
        float cmin0 = 3.0e38f, cmin1 = 3.0e38f;
        #pragma unroll
        for (int i = 0; i < 4; ++i) {
            #pragma unroll
            for (int r = 0; r < 4; ++r) {
                float s1x = ((const float*)&s1v4[i])[r];
                float d0 = fmaxf(s1x + s2v0 - 2.0f * acc[i][0][r], 0.0f);
                float d1 = fmaxf(s1x + s2v1 - 2.0f * acc[i][1][r], 0.0f);
                rmin[i][r] = fminf(rmin[i][r], fminf(d0, d1));
                cmin0 = fminf(cmin0, d0);
                cmin1 = fminf(cmin1, d1);
            }
        }
        cmin0 = fminf(cmin0, __shfl_xor(cmin0, 16, 64));
        cmin0 = fminf(cmin0, __shfl_xor(cmin0, 32, 64));
        cmin1 = fminf(cmin1, __shfl_xor(cmin1, 16, 64));
        cmin1 = fminf(cmin1, __shfl_xor(cmin1, 32, 64));
        if (lane < 16) {
            atomicMin(&cm[mt * 128 + wm + lcol],      __float_as_uint(cmin0));
            atomicMin(&cm[mt * 128 + wm + 16 + lcol], __float_as_uint(cmin1));
        }
    }

    // ---- final rowmin ----
    unsigned int* rm = rowmin + b * NN + n0;
    #pragma unroll
    for (int i = 0; i < 4; ++i) {
        #pragma unroll
        for (int r = 0; r < 4; ++r) {
            float v = rmin[i][r];
            #pragma unroll
            for (int off = 1; off < 16; off <<= 1)
                v = fminf(v, __shfl_xor(v, off, 64));
            if (lcol == 0)
                atomicMin(&rm[wn + i * 16 + lrow + r], __float_as_uint(v));
        }
    }
    #undef LOADB
    #undef COMPUTE
}

// ---------------------------------------------------------------------------
__global__ __launch_bounds__(256) void finalize_kernel(
        const unsigned int* __restrict__ rowmin,
        const unsigned int* __restrict__ colmin,
        float* __restrict__ out) {
    int b = blockIdx.x;
    int tid = threadIdx.x;
    float s = 0.0f;
    for (int i = tid; i < NN; i += 256) s += __uint_as_float(rowmin[b * NN + i]);
    for (int i = tid; i < MM; i += 256) s += __uint_as_float(colmin[b * MM + i]);
    #pragma unroll
    for (int off = 32; off; off >>= 1) s += __shfl_xor(s, off, 64);
    __shared__ float wsum[4];
    if ((tid & 63) == 0) wsum[tid >> 6] = s;
    __syncthreads();
    if (tid == 0) out[b] = (wsum[0] + wsum[1] + wsum[2] + wsum[3]) * (1.0f / 1024.0f);
}

// ---------------------------------------------------------------------------
extern "C" void kernel_launch(void* const* d_in, const int* in_sizes, int n_in,
                              void* d_out, int out_size, void* d_ws, size_t ws_size,
                              hipStream_t stream) {
    const float* h1 = (const float*)d_in[0];
    const float* h2 = (const float*)d_in[1];
    float* out = (float*)d_out;

    char* ws = (char*)d_ws;
    const size_t bf_bytes = (size_t)BB * NN * DD * sizeof(unsigned short); // 16 MB
    __hip_bfloat16* h1b = (__hip_bfloat16*)ws;
    __hip_bfloat16* h2b = (__hip_bfloat16*)(ws + bf_bytes);
    float* sq1 = (float*)(ws + 2 * bf_bytes);
    float* sq2 = sq1 + BB * NN;
    unsigned int* rowmin = (unsigned int*)(sq2 + BB * MM);
    unsigned int* colmin = rowmin + BB * NN;

    hipLaunchKernelGGL(init_minbuf, dim3(256), dim3(256), 0, stream, rowmin);

    hipLaunchKernelGGL(convert_kernel, dim3((BB * NN + BB * MM) / 4), dim3(256), 0, stream,
                       h1, h2, h1b, h2b, sq1, sq2);

    hipLaunchKernelGGL(gemm_kernel, dim3(BB, 8), dim3(512), 0, stream,
                       h1b, h2b, sq1, sq2, rowmin, colmin);

    hipLaunchKernelGGL(finalize_kernel, dim3(BB), dim3(256), 0, stream,
                       rowmin, colmin, out);
}

// Round 6
// 65.326 us; speedup vs baseline: 1.0929x; 1.0929x over previous
//
#include <hip/hip_runtime.h>
#include <hip/hip_bf16.h>
#include <stdint.h>

#define BB 32
#define NN 1024
#define MM 1024
#define DD 256

typedef __attribute__((ext_vector_type(8))) short short8;
typedef __attribute__((ext_vector_type(4))) float floatx4;

__device__ inline unsigned short f2bf(float x) {
    union { __hip_bfloat16 h; unsigned short u; } cv;
    cv.h = __float2bfloat16(x);
    return cv.u;
}

// async global->LDS, 16B/lane. LDS dest = wave-uniform base + lane*16.
__device__ inline void async_copy16(void* lds, const void* g) {
    __builtin_amdgcn_global_load_lds(
        (const __attribute__((address_space(1))) unsigned int*)g,
        (__attribute__((address_space(3))) unsigned int*)lds, 16, 0, 0);
}

// ---------------------------------------------------------------------------
__global__ __launch_bounds__(256) void init_minbuf(unsigned int* __restrict__ p) {
    p[blockIdx.x * 256 + threadIdx.x] = 0x7F800000u; // +inf
}

// ---------------------------------------------------------------------------
// Convert fp32 -> bf16 + per-row sum of squares (fp32 exact). One wave/row.
// ---------------------------------------------------------------------------
__global__ __launch_bounds__(256) void convert_kernel(
        const float* __restrict__ h1, const float* __restrict__ h2,
        __hip_bfloat16* __restrict__ h1b, __hip_bfloat16* __restrict__ h2b,
        float* __restrict__ sq1, float* __restrict__ sq2) {
    int wave = blockIdx.x * 4 + (threadIdx.x >> 6);
    int lane = threadIdx.x & 63;
    const int total1 = BB * NN;

    const float* src;
    __hip_bfloat16* dst;
    float* sq;
    int row;
    if (wave < total1) { src = h1; dst = h1b; sq = sq1; row = wave; }
    else               { src = h2; dst = h2b; sq = sq2; row = wave - total1; }

    const float4* p = (const float4*)(src + (size_t)row * DD);
    float4 v = p[lane];

    float s = v.x * v.x + v.y * v.y + v.z * v.z + v.w * v.w;
    #pragma unroll
    for (int off = 32; off; off >>= 1) s += __shfl_xor(s, off, 64);

    ushort4 o;
    o.x = f2bf(v.x); o.y = f2bf(v.y); o.z = f2bf(v.z); o.w = f2bf(v.w);
    *(ushort4*)((unsigned short*)(dst + (size_t)row * DD) + lane * 4) = o;

    if (lane == 0) sq[row] = s;
}

// ---------------------------------------------------------------------------
// m97-structure batched GEMM + fused Hausdorff epilogue.
// 128x128 tile, BK=64, 4 waves (2x2 of 64x64), single-buffer 32 KB LDS,
// global_load_lds w16 staging, both-sides XOR swizzle, 2 barriers/K-step,
// 3 blocks/CU (cross-block latency hiding, m114-style implicit overlap).
// Grid (batch.x=32, tile.y=64): batch b's blocks all map to XCD b%8.
// ---------------------------------------------------------------------------
__global__ __launch_bounds__(256, 3) void gemm_kernel(
        const __hip_bfloat16* __restrict__ h1b, const __hip_bfloat16* __restrict__ h2b,
        const float* __restrict__ sq1, const float* __restrict__ sq2,
        unsigned int* __restrict__ rowmin, unsigned int* __restrict__ colmin) {
    __shared__ __align__(16) unsigned short As[128 * 64];   // 16 KB
    __shared__ __align__(16) unsigned short Bs[128 * 64];   // 16 KB

    const int b    = blockIdx.x;       // batch
    const int tile = blockIdx.y;       // 0..63
    const int n0   = (tile >> 3) * 128;
    const int m0   = (tile & 7) * 128;

    const int tid  = threadIdx.x;
    const int wave = tid >> 6;
    const int lane = tid & 63;
    const int wn   = (wave >> 1) * 64;
    const int wm   = (wave & 1) * 64;

    const char* Ag = (const char*)(h1b + ((size_t)b * NN + n0) * DD);
    const char* Bg = (const char*)(h2b + ((size_t)b * MM + m0) * DD);

    const int krow = lane >> 4;   // 0..3
    const int rrow = lane & 15;   // 0..15
    const int rx   = rrow & 7;

    // staging: 16 KB tile = 16 chunks of 1 KB (8 rows x 128 B).
    // lane: row-in-chunk = lane>>3; LDS linear at lane*16; global src
    // 16B-unit inverse-XOR-swizzled (unit ^= row&7; row&7 == lane>>3).
    const int rl  = lane >> 3;
    const int bcu = (lane & 7) ^ rl;

    #define STAGE(dst_, Gp_, ks_)                                             \
        {                                                                     \
            _Pragma("unroll")                                                 \
            for (int c = 0; c < 4; ++c) {                                     \
                int ch_ = wave * 4 + c;                                       \
                async_copy16((char*)(dst_) + ch_ * 1024,                      \
                             (Gp_) + (size_t)(ch_ * 8 + rl) * 512             \
                                   + (size_t)(ks_) * 128 + (bcu << 4));       \
            }                                                                 \
        }

    floatx4 acc[4][4] = {};

    #pragma unroll 1
    for (int ks = 0; ks < 4; ++ks) {
        STAGE(As, Ag, ks);
        STAGE(Bs, Bg, ks);
        asm volatile("s_waitcnt vmcnt(0)" ::: "memory");
        __syncthreads();

        const char* Ab = (const char*)As;
        const char* Bb = (const char*)Bs;
        #pragma unroll
        for (int kk = 0; kk < 2; ++kk) {
            const int u = ((kk << 2) | krow) ^ rx;   // swizzled 16B unit
            short8 af[4], bfv[4];
            #pragma unroll
            for (int i = 0; i < 4; ++i)
                af[i] = *(const short8*)(Ab + (size_t)(wn + i * 16 + rrow) * 128 + (u << 4));
            #pragma unroll
            for (int j = 0; j < 4; ++j)
                bfv[j] = *(const short8*)(Bb + (size_t)(wm + j * 16 + rrow) * 128 + (u << 4));
            #pragma unroll
            for (int i = 0; i < 4; ++i)
                #pragma unroll
                for (int j = 0; j < 4; ++j)
                    acc[i][j] = __builtin_amdgcn_mfma_f32_16x16x32_bf16(
                        af[i], bfv[j], acc[i][j], 0, 0, 0);
        }
        __syncthreads();
    }

    // ---- epilogue ----
    // D mapping (16x16x32 bf16): col = lane&15, row = (lane>>4)*4 + reg
    const float* s1 = sq1 + b * NN + n0 + wn;
    const float* s2 = sq2 + b * MM + m0 + wm;
    unsigned int* rm = rowmin + b * NN + n0;
    unsigned int* cm = colmin + b * MM + m0;

    const int lrow = krow * 4;
    const int lcol = rrow;

    float s2v[4];
    #pragma unroll
    for (int j = 0; j < 4; ++j) s2v[j] = s2[j * 16 + lcol];

    float cmin[4] = {3.0e38f, 3.0e38f, 3.0e38f, 3.0e38f};

    #pragma unroll
    for (int i = 0; i < 4; ++i) {
        #pragma unroll
        for (int r = 0; r < 4; ++r) {
            float s1v = s1[i * 16 + lrow + r];
            float pm = 3.0e38f;
            #pragma unroll
            for (int j = 0; j < 4; ++j) {
                float dist = fmaxf(s1v + s2v[j] - 2.0f * acc[i][j][r], 0.0f);
                pm = fminf(pm, dist);
                cmin[j] = fminf(cmin[j], dist);
            }
            #pragma unroll
            for (int off = 1; off < 16; off <<= 1)
                pm = fminf(pm, __shfl_xor(pm, off, 64));
            if (lcol == 0)
                atomicMin(&rm[wn + i * 16 + lrow + r], __float_as_uint(pm));
        }
    }

    #pragma unroll
    for (int j = 0; j < 4; ++j) {
        float c = cmin[j];
        c = fminf(c, __shfl_xor(c, 16, 64));
        c = fminf(c, __shfl_xor(c, 32, 64));
        if (krow == 0)
            atomicMin(&cm[wm + j * 16 + lcol], __float_as_uint(c));
    }
    #undef STAGE
}

// ---------------------------------------------------------------------------
__global__ __launch_bounds__(256) void finalize_kernel(
        const unsigned int* __restrict__ rowmin,
        const unsigned int* __restrict__ colmin,
        float* __restrict__ out) {
    int b = blockIdx.x;
    int tid = threadIdx.x;
    float s = 0.0f;
    for (int i = tid; i < NN; i += 256) s += __uint_as_float(rowmin[b * NN + i]);
    for (int i = tid; i < MM; i += 256) s += __uint_as_float(colmin[b * MM + i]);
    #pragma unroll
    for (int off = 32; off; off >>= 1) s += __shfl_xor(s, off, 64);
    __shared__ float wsum[4];
    if ((tid & 63) == 0) wsum[tid >> 6] = s;
    __syncthreads();
    if (tid == 0) out[b] = (wsum[0] + wsum[1] + wsum[2] + wsum[3]) * (1.0f / 1024.0f);
}

// ---------------------------------------------------------------------------
extern "C" void kernel_launch(void* const* d_in, const int* in_sizes, int n_in,
                              void* d_out, int out_size, void* d_ws, size_t ws_size,
                              hipStream_t stream) {
    const float* h1 = (const float*)d_in[0];
    const float* h2 = (const float*)d_in[1];
    float* out = (float*)d_out;

    char* ws = (char*)d_ws;
    const size_t bf_bytes = (size_t)BB * NN * DD * sizeof(unsigned short); // 16 MB
    __hip_bfloat16* h1b = (__hip_bfloat16*)ws;
    __hip_bfloat16* h2b = (__hip_bfloat16*)(ws + bf_bytes);
    float* sq1 = (float*)(ws + 2 * bf_bytes);
    float* sq2 = sq1 + BB * NN;
    unsigned int* rowmin = (unsigned int*)(sq2 + BB * MM);
    unsigned int* colmin = rowmin + BB * NN;

    hipLaunchKernelGGL(init_minbuf, dim3(256), dim3(256), 0, stream, rowmin);

    hipLaunchKernelGGL(convert_kernel, dim3((BB * NN + BB * MM) / 4), dim3(256), 0, stream,
                       h1, h2, h1b, h2b, sq1, sq2);

    hipLaunchKernelGGL(gemm_kernel, dim3(BB, 64), dim3(256), 0, stream,
                       h1b, h2b, sq1, sq2, rowmin, colmin);

    hipLaunchKernelGGL(finalize_kernel, dim3(BB), dim3(256), 0, stream,
                       rowmin, colmin, out);
}